// Round 1
// baseline (3290.713 us; speedup 1.0000x reference)
//
#include <hip/hip_runtime.h>
#include <cstdint>
#include <cstddef>

// ---------------------------------------------------------------------------
// HippocampusModule: query->adapter->MLP(GELU)->key proj->softmax attention
// over 65536-slot memory -> concat -> retriever MLP(GELU).
// Strategy: everything in fp16 MFMA (16x16x32_f16, fp32 accum).
//  - softmax done unnormalized: P = exp(logits) (logits bounded ~|5|), rowsum
//    computed inside the P@V GEMM with an extra MFMA vs all-ones B fragment.
//  - All GEMMs take B pre-transposed ([N,K], K contiguous) so both A and B
//    fragments are ds_read_b128 from LDS.
//  - global_load_lds width=16 staging; XOR swizzle on 16B granules to avoid
//    16-way LDS bank conflicts on fragment reads.
// ---------------------------------------------------------------------------

#define EMB 768
#define HID 1024
#define MEMN 65536
#define NQ 4096

typedef _Float16 half8 __attribute__((ext_vector_type(8)));
typedef _Float16 half4v __attribute__((ext_vector_type(4)));
typedef float float4v __attribute__((ext_vector_type(4)));

// ---------------- conversion kernels ----------------

__global__ void cvt_f32_to_f16(const float* __restrict__ in,
                               _Float16* __restrict__ out, size_t n) {
  size_t i = ((size_t)blockIdx.x * blockDim.x + threadIdx.x) * 4;
  if (i >= n) return;
  float4 v = *(const float4*)(in + i);
  half4v h;
  h[0] = (_Float16)v.x; h[1] = (_Float16)v.y;
  h[2] = (_Float16)v.z; h[3] = (_Float16)v.w;
  *(half4v*)(out + i) = h;
}

// out[C][R] (fp16) = transpose of in[R][C] (fp32). R,C multiples of 32.
__global__ void transpose_cvt(const float* __restrict__ in,
                              _Float16* __restrict__ out, int R, int C) {
  __shared__ float t[32][33];
  int tx = threadIdx.x, ty = threadIdx.y;
  int c0 = blockIdx.x * 32, r0 = blockIdx.y * 32;
#pragma unroll
  for (int k = 0; k < 4; ++k) {
    int r = r0 + ty + k * 8;
    t[ty + k * 8][tx] = in[(size_t)r * C + c0 + tx];
  }
  __syncthreads();
#pragma unroll
  for (int k = 0; k < 4; ++k) {
    int ro = c0 + ty + k * 8;  // output row == input col
    out[(size_t)ro * R + r0 + tx] = (_Float16)t[tx][ty + k * 8];
  }
}

// ---------------- GEMM ----------------

enum { EPI_H16 = 0, EPI_GELU_H16 = 1, EPI_EXP_H16 = 2, EPI_DIV_H16 = 3, EPI_F32 = 4 };

__device__ __forceinline__ void global_to_lds16(const _Float16* g, _Float16* l) {
  __builtin_amdgcn_global_load_lds(
      (__attribute__((address_space(1))) void*)g,
      (__attribute__((address_space(3))) void*)l, 16, 0, 0);
}

__device__ __forceinline__ float gelu_erf(float x) {
  return 0.5f * x * (1.0f + erff(x * 0.7071067811865475f));
}

// C[M,N] = epilogue(A[M,K] @ BT[N,K]^T).  M,N multiples of 128, K of 64.
// grid = (N/128, M/128), block = 256 (4 waves, 2x2 of 64x64, each 4x4 MFMAs).
template <int EPI>
__global__ __launch_bounds__(256) void gemm_bt(
    const _Float16* __restrict__ A, int lda, const _Float16* __restrict__ BT,
    int ldb, const float* __restrict__ bias, void* __restrict__ Cout, int ldc,
    int K, float scale) {
  __shared__ __align__(16) _Float16 sA[128 * 64];
  __shared__ __align__(16) _Float16 sB[128 * 64];

  const int tid = threadIdx.x;
  const int lane = tid & 63;
  const int wave = tid >> 6;
  const int quad = lane >> 4;
  const int m16 = lane & 15;
  const int wm = (wave >> 1) * 64;  // wave's row quadrant within 128x128
  const int wn = (wave & 1) * 64;   // wave's col quadrant

  const size_t rowBase = (size_t)blockIdx.y * 128;
  const size_t colBase = (size_t)blockIdx.x * 128;

  // Staging: inst t=wave*4+q covers 8 rows (8t..8t+7); lane -> sub-row lane>>3,
  // 16B granule slot lane&7. Granule slot p holds global granule g = p ^ (row&7)
  // (XOR swizzle -> fragment reads are 2-way-conflict max, which is free).
  const int srow = lane >> 3;
  const int sg = (lane & 7) ^ srow;

  const _Float16* Abase[4];
  const _Float16* Bbase[4];
#pragma unroll
  for (int q = 0; q < 4; ++q) {
    int t = wave * 4 + q;
    Abase[q] = A + (rowBase + 8 * t + srow) * (size_t)lda + sg * 8;
    Bbase[q] = BT + (colBase + 8 * t + srow) * (size_t)ldb + sg * 8;
  }

  float4v acc[4][4] = {};
  float4v accrs[4] = {};  // rowsum accumulator (EPI_DIV_H16 only)
  half8 vone;
#pragma unroll
  for (int e = 0; e < 8; ++e) vone[e] = (_Float16)1.0f;

  for (int k0 = 0; k0 < K; k0 += 64) {
    __syncthreads();
#pragma unroll
    for (int q = 0; q < 4; ++q) {
      int t = wave * 4 + q;
      global_to_lds16(Abase[q] + k0, &sA[t * 512 + lane * 8]);
      global_to_lds16(Bbase[q] + k0, &sB[t * 512 + lane * 8]);
    }
    __syncthreads();

#pragma unroll
    for (int kk = 0; kk < 2; ++kk) {
      half8 af[4], bf[4];
      const int pg = kk * 4 + quad;           // wanted global granule
      const int ps = pg ^ (m16 & 7);          // swizzled slot
#pragma unroll
      for (int i = 0; i < 4; ++i) {
        int r = wm + i * 16 + m16;
        af[i] = *(const half8*)&sA[r * 64 + ps * 8];
      }
#pragma unroll
      for (int j = 0; j < 4; ++j) {
        int r = wn + j * 16 + m16;
        bf[j] = *(const half8*)&sB[r * 64 + ps * 8];
      }
#pragma unroll
      for (int i = 0; i < 4; ++i) {
#pragma unroll
        for (int j = 0; j < 4; ++j)
          acc[i][j] =
              __builtin_amdgcn_mfma_f32_16x16x32_f16(af[i], bf[j], acc[i][j], 0, 0, 0);
        if (EPI == EPI_DIV_H16)
          accrs[i] =
              __builtin_amdgcn_mfma_f32_16x16x32_f16(af[i], vone, accrs[i], 0, 0, 0);
      }
    }
  }

  // Epilogue. C/D layout: col = lane&15, row = quad*4 + reg (within 16x16).
#pragma unroll
  for (int i = 0; i < 4; ++i) {
    float inv[4];
    if (EPI == EPI_DIV_H16) {
#pragma unroll
      for (int rr = 0; rr < 4; ++rr) inv[rr] = 1.0f / accrs[i][rr];
    }
#pragma unroll
    for (int j = 0; j < 4; ++j) {
      size_t c = colBase + wn + j * 16 + m16;
      float bv = 0.0f;
      if (EPI == EPI_H16 || EPI == EPI_GELU_H16 || EPI == EPI_F32) bv = bias[c];
#pragma unroll
      for (int rr = 0; rr < 4; ++rr) {
        size_t row = rowBase + wm + i * 16 + quad * 4 + rr;
        float x = acc[i][j][rr];
        if (EPI == EPI_H16 || EPI == EPI_GELU_H16 || EPI == EPI_F32) x += bv;
        if (EPI == EPI_GELU_H16) x = gelu_erf(x);
        if (EPI == EPI_EXP_H16) x = expf(x * scale);
        if (EPI == EPI_DIV_H16) x *= inv[rr];
        if (EPI == EPI_F32)
          ((float*)Cout)[row * (size_t)ldc + c] = x;
        else
          ((_Float16*)Cout)[row * (size_t)ldc + c] = (_Float16)x;
      }
    }
  }
}

// ---------------- launch ----------------

static inline void* wsalloc(char*& p, size_t bytes) {
  void* r = (void*)p;
  p += (bytes + 255) & ~(size_t)255;
  return r;
}

extern "C" void kernel_launch(void* const* d_in, const int* in_sizes, int n_in,
                              void* d_out, int out_size, void* d_ws,
                              size_t ws_size, hipStream_t stream) {
  const float* query = (const float*)d_in[0];
  const float* W_in = (const float*)d_in[1];
  const float* b_in = (const float*)d_in[2];
  const float* W_e1 = (const float*)d_in[3];
  const float* b_e1 = (const float*)d_in[4];
  const float* W_e2 = (const float*)d_in[5];
  const float* b_e2 = (const float*)d_in[6];
  const float* W_k = (const float*)d_in[7];
  const float* b_k = (const float*)d_in[8];
  const float* memk = (const float*)d_in[9];
  const float* memv = (const float*)d_in[10];
  const float* W_r1 = (const float*)d_in[11];
  const float* b_r1 = (const float*)d_in[12];
  const float* W_r2 = (const float*)d_in[13];
  const float* b_r2 = (const float*)d_in[14];
  float* out = (float*)d_out;

  char* p = (char*)d_ws;
  _Float16* q16 = (_Float16*)wsalloc(p, (size_t)NQ * EMB * 2);
  _Float16* WinT = (_Float16*)wsalloc(p, (size_t)HID * EMB * 2);
  _Float16* We1T = (_Float16*)wsalloc(p, (size_t)2 * HID * HID * 2);
  _Float16* We2T = (_Float16*)wsalloc(p, (size_t)HID * 2 * HID * 2);
  _Float16* WkT = (_Float16*)wsalloc(p, (size_t)HID * HID * 2);
  _Float16* Wr1T = (_Float16*)wsalloc(p, (size_t)2 * HID * 2 * HID * 2);
  _Float16* Wr2T = (_Float16*)wsalloc(p, (size_t)EMB * 2 * HID * 2);
  _Float16* memk16 = (_Float16*)wsalloc(p, (size_t)MEMN * HID * 2);
  _Float16* memvT = (_Float16*)wsalloc(p, (size_t)HID * MEMN * 2);
  _Float16* x16 = (_Float16*)wsalloc(p, (size_t)NQ * HID * 2);
  _Float16* h16 = (_Float16*)wsalloc(p, (size_t)NQ * 2 * HID * 2);
  _Float16* key16 = (_Float16*)wsalloc(p, (size_t)NQ * HID * 2);
  _Float16* comb16 = (_Float16*)wsalloc(p, (size_t)NQ * 2 * HID * 2);
  _Float16* r16 = (_Float16*)wsalloc(p, (size_t)NQ * 2 * HID * 2);

  // P buffer: chunk M if ws is too small (constant per ws_size -> graph-safe).
  size_t fixedBytes = (size_t)(p - (char*)d_ws);
  size_t Mc = NQ;
  while (Mc > 128 && fixedBytes + Mc * (size_t)MEMN * 2 > ws_size) Mc >>= 1;
  _Float16* P16 = (_Float16*)wsalloc(p, Mc * (size_t)MEMN * 2);

  auto cvt = [&](const float* in, _Float16* o, size_t n) {
    cvt_f32_to_f16<<<dim3((unsigned)((n / 4 + 255) / 256)), 256, 0, stream>>>(in, o, n);
  };
  auto tr = [&](const float* in, _Float16* o, int R, int C) {
    transpose_cvt<<<dim3(C / 32, R / 32), dim3(32, 8), 0, stream>>>(in, o, R, C);
  };

  cvt(query, q16, (size_t)NQ * EMB);
  cvt(memk, memk16, (size_t)MEMN * HID);
  tr(W_in, WinT, EMB, HID);
  tr(W_e1, We1T, HID, 2 * HID);
  tr(W_e2, We2T, 2 * HID, HID);
  tr(W_k, WkT, HID, HID);
  tr(W_r1, Wr1T, 2 * HID, 2 * HID);
  tr(W_r2, Wr2T, 2 * HID, EMB);
  tr(memv, memvT, MEMN, HID);

  // x = query @ W_in + b_in
  gemm_bt<EPI_H16><<<dim3(HID / 128, NQ / 128), 256, 0, stream>>>(
      q16, EMB, WinT, EMB, b_in, x16, HID, EMB, 0.f);
  // h = gelu(x @ W_e1 + b_e1)
  gemm_bt<EPI_GELU_H16><<<dim3(2 * HID / 128, NQ / 128), 256, 0, stream>>>(
      x16, HID, We1T, HID, b_e1, h16, 2 * HID, HID, 0.f);
  // encoded = h @ W_e2 + b_e2  -> left half of combined (ldc = 2*HID)
  gemm_bt<EPI_H16><<<dim3(HID / 128, NQ / 128), 256, 0, stream>>>(
      h16, 2 * HID, We2T, 2 * HID, b_e2, comb16, 2 * HID, 2 * HID, 0.f);
  // key = encoded @ W_k + b_k   (A = combined left half via lda = 2*HID)
  gemm_bt<EPI_H16><<<dim3(HID / 128, NQ / 128), 256, 0, stream>>>(
      comb16, 2 * HID, WkT, HID, b_k, key16, HID, HID, 0.f);

  const float scale = 0.03125f;  // 1/sqrt(HID)
  for (size_t m0 = 0; m0 < NQ; m0 += Mc) {
    // P = exp(scale * key @ memk^T)   [Mc, MEMN] fp16
    gemm_bt<EPI_EXP_H16><<<dim3(MEMN / 128, (unsigned)(Mc / 128)), 256, 0, stream>>>(
        key16 + m0 * HID, HID, memk16, HID, nullptr, P16, MEMN, HID, scale);
    // retrieved = (P @ memv) / rowsum(P) -> right half of combined
    gemm_bt<EPI_DIV_H16><<<dim3(HID / 128, (unsigned)(Mc / 128)), 256, 0, stream>>>(
        P16, MEMN, memvT, MEMN, nullptr, comb16 + m0 * 2 * HID + HID, 2 * HID,
        MEMN, 0.f);
  }

  // r = gelu(combined @ W_r1 + b_r1)
  gemm_bt<EPI_GELU_H16><<<dim3(2 * HID / 128, NQ / 128), 256, 0, stream>>>(
      comb16, 2 * HID, Wr1T, 2 * HID, b_r1, r16, 2 * HID, 2 * HID, 0.f);
  // result = r @ W_r2 + b_r2  (fp32 out)
  gemm_bt<EPI_F32><<<dim3(EMB / 128, NQ / 128), 256, 0, stream>>>(
      r16, 2 * HID, Wr2T, 2 * HID, b_r2, out, EMB, 2 * HID, 0.f);

  (void)in_sizes; (void)n_in; (void)out_size;
}

// Round 2
// 2498.772 us; speedup vs baseline: 1.3169x; 1.3169x over previous
//
#include <hip/hip_runtime.h>
#include <cstdint>
#include <cstddef>

// ---------------------------------------------------------------------------
// HippocampusModule: query->adapter->MLP(GELU)->key proj->softmax attention
// over 65536-slot memory -> concat -> retriever MLP(GELU).
// Strategy: everything in fp16 MFMA (16x16x32_f16, fp32 accum).
//  - softmax unnormalized: P = exp(logits) (bounded), rowsum via ones-MFMA.
//  - R1 result: P@V GEMM (K=65536, grid 256) was latency-bound at 12%
//    occupancy (1 block/CU). R2: split-K (KS=8) + fp32 atomicAdd accumulation
//    + XCD-affinity grid swizzle; normalize in a cheap epilogue kernel.
// ---------------------------------------------------------------------------

#define EMB 768
#define HID 1024
#define MEMN 65536
#define NQ 4096
#define KSPLIT 8

typedef _Float16 half8 __attribute__((ext_vector_type(8)));
typedef _Float16 half4v __attribute__((ext_vector_type(4)));
typedef float float4v __attribute__((ext_vector_type(4)));

// ---------------- conversion kernels ----------------

__global__ void cvt_f32_to_f16(const float* __restrict__ in,
                               _Float16* __restrict__ out, size_t n) {
  size_t i = ((size_t)blockIdx.x * blockDim.x + threadIdx.x) * 4;
  if (i >= n) return;
  float4 v = *(const float4*)(in + i);
  half4v h;
  h[0] = (_Float16)v.x; h[1] = (_Float16)v.y;
  h[2] = (_Float16)v.z; h[3] = (_Float16)v.w;
  *(half4v*)(out + i) = h;
}

// out[C][R] (fp16) = transpose of in[R][C] (fp32). R,C multiples of 32.
__global__ void transpose_cvt(const float* __restrict__ in,
                              _Float16* __restrict__ out, int R, int C) {
  __shared__ float t[32][33];
  int tx = threadIdx.x, ty = threadIdx.y;
  int c0 = blockIdx.x * 32, r0 = blockIdx.y * 32;
#pragma unroll
  for (int k = 0; k < 4; ++k) {
    int r = r0 + ty + k * 8;
    t[ty + k * 8][tx] = in[(size_t)r * C + c0 + tx];
  }
  __syncthreads();
#pragma unroll
  for (int k = 0; k < 4; ++k) {
    int ro = c0 + ty + k * 8;  // output row == input col
    out[(size_t)ro * R + r0 + tx] = (_Float16)t[tx][ty + k * 8];
  }
}

// comb16 right half = fp16(O32 / rs32)
__global__ void normalize_out(const float* __restrict__ O32,
                              const float* __restrict__ rs32,
                              _Float16* __restrict__ comb) {
  size_t i = ((size_t)blockIdx.x * blockDim.x + threadIdx.x) * 4;
  size_t row = i >> 10;
  size_t c = i & 1023;
  float4 v = *(const float4*)(O32 + i);
  float inv = 1.0f / rs32[row];
  half4v h;
  h[0] = (_Float16)(v.x * inv); h[1] = (_Float16)(v.y * inv);
  h[2] = (_Float16)(v.z * inv); h[3] = (_Float16)(v.w * inv);
  *(half4v*)(comb + row * 2048 + 1024 + c) = h;
}

// ---------------- GEMM ----------------

enum { EPI_H16 = 0, EPI_GELU_H16 = 1, EPI_EXP_H16 = 2, EPI_F32 = 4 };

__device__ __forceinline__ void global_to_lds16(const _Float16* g, _Float16* l) {
  __builtin_amdgcn_global_load_lds(
      (__attribute__((address_space(1))) void*)g,
      (__attribute__((address_space(3))) void*)l, 16, 0, 0);
}

__device__ __forceinline__ float gelu_erf(float x) {
  return 0.5f * x * (1.0f + erff(x * 0.7071067811865475f));
}

// C[M,N] = epilogue(A[M,K] @ BT[N,K]^T).  M,N multiples of 128, K of 64.
// grid = (N/128, M/128), block = 256 (4 waves, 2x2 of 64x64, each 4x4 MFMAs).
template <int EPI>
__global__ __launch_bounds__(256) void gemm_bt(
    const _Float16* __restrict__ A, int lda, const _Float16* __restrict__ BT,
    int ldb, const float* __restrict__ bias, void* __restrict__ Cout, int ldc,
    int K, float scale) {
  __shared__ __align__(16) _Float16 sA[128 * 64];
  __shared__ __align__(16) _Float16 sB[128 * 64];

  const int tid = threadIdx.x;
  const int lane = tid & 63;
  const int wave = tid >> 6;
  const int quad = lane >> 4;
  const int m16 = lane & 15;
  const int wm = (wave >> 1) * 64;
  const int wn = (wave & 1) * 64;

  const size_t rowBase = (size_t)blockIdx.y * 128;
  const size_t colBase = (size_t)blockIdx.x * 128;

  const int srow = lane >> 3;
  const int sg = (lane & 7) ^ srow;  // XOR-swizzled 16B granule slot

  const _Float16* Abase[4];
  const _Float16* Bbase[4];
#pragma unroll
  for (int q = 0; q < 4; ++q) {
    int t = wave * 4 + q;
    Abase[q] = A + (rowBase + 8 * t + srow) * (size_t)lda + sg * 8;
    Bbase[q] = BT + (colBase + 8 * t + srow) * (size_t)ldb + sg * 8;
  }

  float4v acc[4][4] = {};

  for (int k0 = 0; k0 < K; k0 += 64) {
    __syncthreads();
#pragma unroll
    for (int q = 0; q < 4; ++q) {
      int t = wave * 4 + q;
      global_to_lds16(Abase[q] + k0, &sA[t * 512 + lane * 8]);
      global_to_lds16(Bbase[q] + k0, &sB[t * 512 + lane * 8]);
    }
    __syncthreads();

#pragma unroll
    for (int kk = 0; kk < 2; ++kk) {
      half8 af[4], bf[4];
      const int pg = kk * 4 + quad;
      const int ps = pg ^ (m16 & 7);
#pragma unroll
      for (int i = 0; i < 4; ++i)
        af[i] = *(const half8*)&sA[(wm + i * 16 + m16) * 64 + ps * 8];
#pragma unroll
      for (int j = 0; j < 4; ++j)
        bf[j] = *(const half8*)&sB[(wn + j * 16 + m16) * 64 + ps * 8];
#pragma unroll
      for (int i = 0; i < 4; ++i)
#pragma unroll
        for (int j = 0; j < 4; ++j)
          acc[i][j] =
              __builtin_amdgcn_mfma_f32_16x16x32_f16(af[i], bf[j], acc[i][j], 0, 0, 0);
    }
  }

  // Epilogue. C/D layout: col = lane&15, row = quad*4 + reg (within 16x16).
#pragma unroll
  for (int i = 0; i < 4; ++i) {
#pragma unroll
    for (int j = 0; j < 4; ++j) {
      size_t c = colBase + wn + j * 16 + m16;
      float bv = (EPI == EPI_EXP_H16) ? 0.0f : bias[c];
#pragma unroll
      for (int rr = 0; rr < 4; ++rr) {
        size_t row = rowBase + wm + i * 16 + quad * 4 + rr;
        float x = acc[i][j][rr];
        if (EPI != EPI_EXP_H16) x += bv;
        if (EPI == EPI_GELU_H16) x = gelu_erf(x);
        if (EPI == EPI_EXP_H16) x = expf(x * scale);
        if (EPI == EPI_F32)
          ((float*)Cout)[row * (size_t)ldc + c] = x;
        else
          ((_Float16*)Cout)[row * (size_t)ldc + c] = (_Float16)x;
      }
    }
  }
}

// Split-K P@V: O32[M,1024] += P[M,K] @ VT[1024,K]^T (fp32 atomics),
// rs32[M] += rowsum(P) via ones-MFMA (n-block 0 only).
// 1-D grid, id decode puts the 8 N-blocks of one (m,kslice) group on ids that
// are congruent mod 8 -> same XCD -> shared-L2 A-slice reuse.
__global__ __launch_bounds__(256) void gemm_pv_splitk(
    const _Float16* __restrict__ P, const _Float16* __restrict__ VT,
    float* __restrict__ O32, float* __restrict__ rs32, int Kslice,
    int mBlocks) {
  __shared__ __align__(16) _Float16 sA[128 * 64];
  __shared__ __align__(16) _Float16 sB[128 * 64];

  const int id = blockIdx.x;
  const int c8 = id & 7;
  const int nb = (id >> 3) & 7;
  const int g = (id >> 6) * 8 + c8;  // group = (m, kslice)
  const int mb = g % mBlocks;
  const int ks = g / mBlocks;

  const int tid = threadIdx.x;
  const int lane = tid & 63;
  const int wave = tid >> 6;
  const int quad = lane >> 4;
  const int m16 = lane & 15;
  const int wm = (wave >> 1) * 64;
  const int wn = (wave & 1) * 64;

  const size_t rowBase = (size_t)mb * 128;
  const size_t colBase = (size_t)nb * 128;
  const int kBeg = ks * Kslice;

  const int srow = lane >> 3;
  const int sg = (lane & 7) ^ srow;

  const _Float16* Abase[4];
  const _Float16* Bbase[4];
#pragma unroll
  for (int q = 0; q < 4; ++q) {
    int t = wave * 4 + q;
    Abase[q] = P + (rowBase + 8 * t + srow) * (size_t)MEMN + kBeg + sg * 8;
    Bbase[q] = VT + (colBase + 8 * t + srow) * (size_t)MEMN + kBeg + sg * 8;
  }

  float4v acc[4][4] = {};
  float4v accrs[4] = {};
  const bool doRS = (nb == 0);
  half8 vone;
#pragma unroll
  for (int e = 0; e < 8; ++e) vone[e] = (_Float16)1.0f;

  for (int k0 = 0; k0 < Kslice; k0 += 64) {
    __syncthreads();
#pragma unroll
    for (int q = 0; q < 4; ++q) {
      int t = wave * 4 + q;
      global_to_lds16(Abase[q] + k0, &sA[t * 512 + lane * 8]);
      global_to_lds16(Bbase[q] + k0, &sB[t * 512 + lane * 8]);
    }
    __syncthreads();

#pragma unroll
    for (int kk = 0; kk < 2; ++kk) {
      half8 af[4], bf[4];
      const int pg = kk * 4 + quad;
      const int ps = pg ^ (m16 & 7);
#pragma unroll
      for (int i = 0; i < 4; ++i)
        af[i] = *(const half8*)&sA[(wm + i * 16 + m16) * 64 + ps * 8];
#pragma unroll
      for (int j = 0; j < 4; ++j)
        bf[j] = *(const half8*)&sB[(wn + j * 16 + m16) * 64 + ps * 8];
#pragma unroll
      for (int i = 0; i < 4; ++i) {
#pragma unroll
        for (int j = 0; j < 4; ++j)
          acc[i][j] =
              __builtin_amdgcn_mfma_f32_16x16x32_f16(af[i], bf[j], acc[i][j], 0, 0, 0);
        if (doRS)
          accrs[i] =
              __builtin_amdgcn_mfma_f32_16x16x32_f16(af[i], vone, accrs[i], 0, 0, 0);
      }
    }
  }

#pragma unroll
  for (int i = 0; i < 4; ++i) {
#pragma unroll
    for (int j = 0; j < 4; ++j) {
      size_t c = colBase + wn + j * 16 + m16;
#pragma unroll
      for (int rr = 0; rr < 4; ++rr) {
        size_t row = rowBase + wm + i * 16 + quad * 4 + rr;
        atomicAdd(&O32[row * 1024 + c], acc[i][j][rr]);
      }
    }
    if (doRS && m16 == 0) {
#pragma unroll
      for (int rr = 0; rr < 4; ++rr) {
        size_t row = rowBase + wm + i * 16 + quad * 4 + rr;
        atomicAdd(&rs32[row], accrs[i][rr]);
      }
    }
  }
}

// ---------------- launch ----------------

static inline void* wsalloc(char*& p, size_t bytes) {
  void* r = (void*)p;
  p += (bytes + 255) & ~(size_t)255;
  return r;
}

extern "C" void kernel_launch(void* const* d_in, const int* in_sizes, int n_in,
                              void* d_out, int out_size, void* d_ws,
                              size_t ws_size, hipStream_t stream) {
  const float* query = (const float*)d_in[0];
  const float* W_in = (const float*)d_in[1];
  const float* b_in = (const float*)d_in[2];
  const float* W_e1 = (const float*)d_in[3];
  const float* b_e1 = (const float*)d_in[4];
  const float* W_e2 = (const float*)d_in[5];
  const float* b_e2 = (const float*)d_in[6];
  const float* W_k = (const float*)d_in[7];
  const float* b_k = (const float*)d_in[8];
  const float* memk = (const float*)d_in[9];
  const float* memv = (const float*)d_in[10];
  const float* W_r1 = (const float*)d_in[11];
  const float* b_r1 = (const float*)d_in[12];
  const float* W_r2 = (const float*)d_in[13];
  const float* b_r2 = (const float*)d_in[14];
  float* out = (float*)d_out;

  char* p = (char*)d_ws;
  _Float16* q16 = (_Float16*)wsalloc(p, (size_t)NQ * EMB * 2);
  _Float16* WinT = (_Float16*)wsalloc(p, (size_t)HID * EMB * 2);
  _Float16* We1T = (_Float16*)wsalloc(p, (size_t)2 * HID * HID * 2);
  _Float16* We2T = (_Float16*)wsalloc(p, (size_t)HID * 2 * HID * 2);
  _Float16* WkT = (_Float16*)wsalloc(p, (size_t)HID * HID * 2);
  _Float16* Wr1T = (_Float16*)wsalloc(p, (size_t)2 * HID * 2 * HID * 2);
  _Float16* Wr2T = (_Float16*)wsalloc(p, (size_t)EMB * 2 * HID * 2);
  _Float16* memk16 = (_Float16*)wsalloc(p, (size_t)MEMN * HID * 2);
  _Float16* memvT = (_Float16*)wsalloc(p, (size_t)HID * MEMN * 2);
  _Float16* x16 = (_Float16*)wsalloc(p, (size_t)NQ * HID * 2);
  _Float16* h16 = (_Float16*)wsalloc(p, (size_t)NQ * 2 * HID * 2);
  _Float16* key16 = (_Float16*)wsalloc(p, (size_t)NQ * HID * 2);
  _Float16* comb16 = (_Float16*)wsalloc(p, (size_t)NQ * 2 * HID * 2);
  _Float16* r16 = (_Float16*)wsalloc(p, (size_t)NQ * 2 * HID * 2);
  float* O32 = (float*)wsalloc(p, (size_t)NQ * HID * 4);
  float* rs32 = (float*)wsalloc(p, (size_t)NQ * 4);

  // P buffer: chunk M if ws is too small (constant per ws_size -> graph-safe).
  size_t fixedBytes = (size_t)(p - (char*)d_ws);
  size_t Mc = NQ;
  while (Mc > 128 && fixedBytes + Mc * (size_t)MEMN * 2 > ws_size) Mc >>= 1;
  _Float16* P16 = (_Float16*)wsalloc(p, Mc * (size_t)MEMN * 2);

  auto cvt = [&](const float* in, _Float16* o, size_t n) {
    cvt_f32_to_f16<<<dim3((unsigned)((n / 4 + 255) / 256)), 256, 0, stream>>>(in, o, n);
  };
  auto tr = [&](const float* in, _Float16* o, int R, int C) {
    transpose_cvt<<<dim3(C / 32, R / 32), dim3(32, 8), 0, stream>>>(in, o, R, C);
  };

  cvt(query, q16, (size_t)NQ * EMB);
  cvt(memk, memk16, (size_t)MEMN * HID);
  tr(W_in, WinT, EMB, HID);
  tr(W_e1, We1T, HID, 2 * HID);
  tr(W_e2, We2T, 2 * HID, HID);
  tr(W_k, WkT, HID, HID);
  tr(W_r1, Wr1T, 2 * HID, 2 * HID);
  tr(W_r2, Wr2T, 2 * HID, EMB);
  tr(memv, memvT, MEMN, HID);

  // x = query @ W_in + b_in
  gemm_bt<EPI_H16><<<dim3(HID / 128, NQ / 128), 256, 0, stream>>>(
      q16, EMB, WinT, EMB, b_in, x16, HID, EMB, 0.f);
  // h = gelu(x @ W_e1 + b_e1)
  gemm_bt<EPI_GELU_H16><<<dim3(2 * HID / 128, NQ / 128), 256, 0, stream>>>(
      x16, HID, We1T, HID, b_e1, h16, 2 * HID, HID, 0.f);
  // encoded = h @ W_e2 + b_e2  -> left half of combined (ldc = 2*HID)
  gemm_bt<EPI_H16><<<dim3(HID / 128, NQ / 128), 256, 0, stream>>>(
      h16, 2 * HID, We2T, 2 * HID, b_e2, comb16, 2 * HID, 2 * HID, 0.f);
  // key = encoded @ W_k + b_k   (A = combined left half via lda = 2*HID)
  gemm_bt<EPI_H16><<<dim3(HID / 128, NQ / 128), 256, 0, stream>>>(
      comb16, 2 * HID, WkT, HID, b_k, key16, HID, HID, 0.f);

  // zero attention accumulators (harness poisons ws every call)
  hipMemsetAsync(O32, 0, (size_t)NQ * HID * 4, stream);
  hipMemsetAsync(rs32, 0, (size_t)NQ * 4, stream);

  const float scale = 0.03125f;  // 1/sqrt(HID)
  const int Kslice = MEMN / KSPLIT;
  for (size_t m0 = 0; m0 < NQ; m0 += Mc) {
    // P = exp(scale * key @ memk^T)   [Mc, MEMN] fp16
    gemm_bt<EPI_EXP_H16><<<dim3(MEMN / 128, (unsigned)(Mc / 128)), 256, 0, stream>>>(
        key16 + m0 * HID, HID, memk16, HID, nullptr, P16, MEMN, HID, scale);
    // O32[m0..] += P @ memv (split-K, fp32 atomics); rs32 += rowsum(P)
    int mBlocks = (int)(Mc / 128);
    gemm_pv_splitk<<<dim3((unsigned)(mBlocks * KSPLIT * 8)), 256, 0, stream>>>(
        P16, memvT, O32 + m0 * HID, rs32 + m0, Kslice, mBlocks);
  }

  // retrieved = O32 / rs32 -> right half of combined
  normalize_out<<<dim3(NQ * HID / 4 / 256), 256, 0, stream>>>(O32, rs32, comb16);

  // r = gelu(combined @ W_r1 + b_r1)
  gemm_bt<EPI_GELU_H16><<<dim3(2 * HID / 128, NQ / 128), 256, 0, stream>>>(
      comb16, 2 * HID, Wr1T, 2 * HID, b_r1, r16, 2 * HID, 2 * HID, 0.f);
  // result = r @ W_r2 + b_r2  (fp32 out)
  gemm_bt<EPI_F32><<<dim3(EMB / 128, NQ / 128), 256, 0, stream>>>(
      r16, 2 * HID, Wr2T, 2 * HID, b_r2, out, EMB, 2 * HID, 0.f);

  (void)in_sizes; (void)n_in; (void)out_size;
}